// Round 7
// baseline (923.123 us; speedup 1.0000x reference)
//
#include <hip/hip_runtime.h>

#define N_ROWS 16384
#define OBS    1024
#define HID    2048
#define LAT    256
#define VOCAB  8192
#define HQ     4
#define LN_EPS 1e-5f

typedef unsigned short u16;
typedef unsigned long long u64;
typedef __bf16 bf16x8 __attribute__((ext_vector_type(8)));
typedef float  f32x4  __attribute__((ext_vector_type(4)));

static __device__ __forceinline__ unsigned int float_to_ordered(float f) {
    unsigned int u = __float_as_uint(f);
    return (u & 0x80000000u) ? ~u : (u | 0x80000000u);
}
// fp32 -> bf16 round-to-nearest-even
static __device__ __forceinline__ u16 f2bf(float f) {
    unsigned int u = __float_as_uint(f);
    unsigned int r = u + 0x7FFFu + ((u >> 16) & 1u);
    return (u16)(r >> 16);
}
static __device__ __forceinline__ float bf2f(u16 u) {
    return __uint_as_float((unsigned int)u << 16);
}

#define GL2LDS(gp, lp) __builtin_amdgcn_global_load_lds( \
    (const __attribute__((address_space(1))) void*)(gp), \
    (__attribute__((address_space(3))) void*)(lp), 16, 0, 0)

// ---------------------------------------------------------------------------
// bf16 MFMA GEMM, 128x128 tile, C = A @ B^T + bias. (verified rounds 3-6)
// EPI 0: store bf16 C.  1: relu + store bf16 C.  3: fused loss, no store.
// ---------------------------------------------------------------------------
template<int EPI>
__global__ __launch_bounds__(256, 4) void mfma_gemm_k(
    const u16* __restrict__ Abf, const u16* __restrict__ Bbf,
    const float* __restrict__ bias,
    u16* __restrict__ Cbf,
    const float* __restrict__ X, double* __restrict__ lacc,
    int K, int Nd)
{
    __shared__ u16 As[128 * 64];
    __shared__ u16 Bs[128 * 64];

    const int tid  = threadIdx.x;
    const int wv   = tid >> 6, lane = tid & 63;
    const int wm   = wv & 1,   wn   = wv >> 1;
    const int m_   = lane & 15, g   = lane >> 4;
    const int m0   = blockIdx.x * 128;
    const int n0   = blockIdx.y * 128;

    f32x4 acc[4][4];
#pragma unroll
    for (int i = 0; i < 4; ++i)
#pragma unroll
        for (int j = 0; j < 4; ++j)
            acc[i][j] = f32x4{0.f, 0.f, 0.f, 0.f};

    const u16* Ablk = Abf + (size_t)m0 * K;
    const u16* Bblk = Bbf + (size_t)n0 * K;

    for (int k0 = 0; k0 < K; k0 += 64) {
#pragma unroll
        for (int c = 0; c < 4; ++c) {
            const int ci = (wv * 4 + c) * 64 + lane;
            const int r  = ci >> 3;
            const int cc = ci & 7;
            const int kc = (cc ^ (r & 7)) << 3;
            GL2LDS(Ablk + (size_t)r * K + k0 + kc, As + (wv * 4 + c) * 512);
            GL2LDS(Bblk + (size_t)r * K + k0 + kc, Bs + (wv * 4 + c) * 512);
        }
        __syncthreads();
#pragma unroll
        for (int ks = 0; ks < 2; ++ks) {
            const int ccw = ks * 4 + g;
            const int sw  = (ccw ^ (m_ & 7)) << 3;
            bf16x8 af[4], bfr[4];
#pragma unroll
            for (int t = 0; t < 4; ++t) {
                af[t]  = *(const bf16x8*)&As[(wm * 64 + t * 16 + m_) * 64 + sw];
                bfr[t] = *(const bf16x8*)&Bs[(wn * 64 + t * 16 + m_) * 64 + sw];
            }
#pragma unroll
            for (int mi = 0; mi < 4; ++mi)
#pragma unroll
                for (int ni = 0; ni < 4; ++ni)
                    acc[mi][ni] = __builtin_amdgcn_mfma_f32_16x16x32_bf16(
                        af[mi], bfr[ni], acc[mi][ni], 0, 0, 0);
        }
        __syncthreads();
    }

    float bs[4];
#pragma unroll
    for (int ni = 0; ni < 4; ++ni) bs[ni] = bias[n0 + wn * 64 + ni * 16 + m_];

    if constexpr (EPI == 3) {
        float lsum = 0.f;
#pragma unroll
        for (int mi = 0; mi < 4; ++mi)
#pragma unroll
            for (int j = 0; j < 4; ++j) {
                const int row = m0 + wm * 64 + mi * 16 + g * 4 + j;
#pragma unroll
                for (int ni = 0; ni < 4; ++ni) {
                    const int col = n0 + wn * 64 + ni * 16 + m_;
                    float r = acc[mi][ni][j] + bs[ni] - X[(size_t)row * Nd + col];
                    lsum = fmaf(r, r, lsum);
                }
            }
#pragma unroll
        for (int off = 32; off >= 1; off >>= 1) lsum += __shfl_xor(lsum, off);
        __shared__ float red[4];
        if (lane == 0) red[wv] = lsum;
        __syncthreads();
        if (tid == 0)
            atomicAdd(lacc, (double)(red[0] + red[1] + red[2] + red[3]));
    } else {
#pragma unroll
        for (int mi = 0; mi < 4; ++mi)
#pragma unroll
            for (int j = 0; j < 4; ++j) {
                const int row = m0 + wm * 64 + mi * 16 + g * 4 + j;
#pragma unroll
                for (int ni = 0; ni < 4; ++ni) {
                    const int col = n0 + wn * 64 + ni * 16 + m_;
                    float v = acc[mi][ni][j] + bs[ni];
                    if constexpr (EPI == 1) v = fmaxf(v, 0.f);
                    Cbf[(size_t)row * Nd + col] = f2bf(v);
                }
            }
    }
}

// ---------------------------------------------------------------------------
// GEMM2 dedicated kernel: 64x64 tile (N=256 gives only 2 column-tiles at 128
// width -> 256 blocks = 1/CU; 64-tiles give 1024 blocks = 4/CU).
// latent = h @ w2T^T + b2; writes fp32 latent + fp32 resid + bf16 rbf.
// ---------------------------------------------------------------------------
__global__ __launch_bounds__(256, 4) void gemm2_k(
    const u16* __restrict__ Abf, const u16* __restrict__ Bbf,
    const float* __restrict__ bias,
    float* __restrict__ lat, float* __restrict__ resid, u16* __restrict__ rbf)
{
    __shared__ u16 As[64 * 64];
    __shared__ u16 Bs[64 * 64];

    const int tid = threadIdx.x;
    const int wv  = tid >> 6, lane = tid & 63;
    const int wm  = wv & 1,   wn   = wv >> 1;
    const int m_  = lane & 15, g   = lane >> 4;
    const int m0  = blockIdx.x * 64;
    const int n0  = blockIdx.y * 64;

    f32x4 acc[2][2];
#pragma unroll
    for (int i = 0; i < 2; ++i)
#pragma unroll
        for (int j = 0; j < 2; ++j)
            acc[i][j] = f32x4{0.f, 0.f, 0.f, 0.f};

    const u16* Ablk = Abf + (size_t)m0 * HID;
    const u16* Bblk = Bbf + (size_t)n0 * HID;

    for (int k0 = 0; k0 < HID; k0 += 64) {
#pragma unroll
        for (int c = 0; c < 2; ++c) {
            const int ci = (wv * 2 + c) * 64 + lane;
            const int r  = ci >> 3;
            const int cc = ci & 7;
            const int kc = (cc ^ (r & 7)) << 3;
            GL2LDS(Ablk + (size_t)r * HID + k0 + kc, As + (wv * 2 + c) * 512);
            GL2LDS(Bblk + (size_t)r * HID + k0 + kc, Bs + (wv * 2 + c) * 512);
        }
        __syncthreads();
#pragma unroll
        for (int ks = 0; ks < 2; ++ks) {
            const int ccw = ks * 4 + g;
            const int sw  = (ccw ^ (m_ & 7)) << 3;
            bf16x8 af[2], bfr[2];
#pragma unroll
            for (int t = 0; t < 2; ++t) {
                af[t]  = *(const bf16x8*)&As[(wm * 32 + t * 16 + m_) * 64 + sw];
                bfr[t] = *(const bf16x8*)&Bs[(wn * 32 + t * 16 + m_) * 64 + sw];
            }
#pragma unroll
            for (int mi = 0; mi < 2; ++mi)
#pragma unroll
                for (int ni = 0; ni < 2; ++ni)
                    acc[mi][ni] = __builtin_amdgcn_mfma_f32_16x16x32_bf16(
                        af[mi], bfr[ni], acc[mi][ni], 0, 0, 0);
        }
        __syncthreads();
    }

#pragma unroll
    for (int mi = 0; mi < 2; ++mi)
#pragma unroll
        for (int j = 0; j < 4; ++j) {
            const int row = m0 + wm * 32 + mi * 16 + g * 4 + j;
#pragma unroll
            for (int ni = 0; ni < 2; ++ni) {
                const int col = n0 + wn * 32 + ni * 16 + m_;
                float v = acc[mi][ni][j] + bias[col];
                lat  [(size_t)row * LAT + col] = v;
                resid[(size_t)row * LAT + col] = v;
                rbf  [(size_t)row * LAT + col] = f2bf(v);
            }
        }
}

// ---------------------------------------------------------------------------
// Transpose + convert weights: W fp32 [K,N] -> Wt bf16 [N,K]
// ---------------------------------------------------------------------------
__global__ __launch_bounds__(256) void tpose_bf_k(
    const float* __restrict__ W, u16* __restrict__ Wt, int K, int N)
{
    __shared__ u16 t[32][33];
    const int lx = threadIdx.x & 31, ly = threadIdx.x >> 5;
    const int n0 = blockIdx.x * 32, k0 = blockIdx.y * 32;
#pragma unroll
    for (int i = 0; i < 4; ++i)
        t[ly + 8 * i][lx] = f2bf(W[(size_t)(k0 + ly + 8 * i) * N + n0 + lx]);
    __syncthreads();
#pragma unroll
    for (int i = 0; i < 4; ++i)
        Wt[(size_t)(n0 + ly + 8 * i) * K + k0 + lx] = t[lx][ly + 8 * i];
}

// ---------------------------------------------------------------------------
// LayerNorm + ReLU in place on bf16 h (fp32 math), one block per row of 2048.
// ---------------------------------------------------------------------------
__device__ __forceinline__ float block_reduce_bcast(float v, float* scratch) {
#pragma unroll
    for (int off = 32; off >= 1; off >>= 1) v += __shfl_xor(v, off);
    const int tid = threadIdx.x;
    __syncthreads();
    if ((tid & 63) == 0) scratch[tid >> 6] = v;
    __syncthreads();
    return scratch[0] + scratch[1] + scratch[2] + scratch[3];
}

__global__ __launch_bounds__(256) void ln_relu_bf_k(
    u16* __restrict__ h, const float* __restrict__ g, const float* __restrict__ b)
{
    __shared__ float scratch[4];
    const int tid = threadIdx.x;
    u16* hp = h + (size_t)blockIdx.x * HID + tid * 8;

    ushort4 r0 = *(const ushort4*)hp;
    ushort4 r1 = *(const ushort4*)(hp + 4);
    float v[8] = {bf2f(r0.x), bf2f(r0.y), bf2f(r0.z), bf2f(r0.w),
                  bf2f(r1.x), bf2f(r1.y), bf2f(r1.z), bf2f(r1.w)};

    float s = 0.f;
#pragma unroll
    for (int e = 0; e < 8; ++e) s += v[e];
    const float mu = block_reduce_bcast(s, scratch) * (1.f / HID);

    float vs = 0.f;
#pragma unroll
    for (int e = 0; e < 8; ++e) { float d = v[e] - mu; vs = fmaf(d, d, vs); }
    const float var = block_reduce_bcast(vs, scratch) * (1.f / HID);
    const float rs = rsqrtf(var + LN_EPS);

    ushort4 o0, o1;
#pragma unroll
    for (int e = 0; e < 8; ++e) {
        const int col = tid * 8 + e;
        float w = (v[e] - mu) * rs * g[col] + b[col];
        w = fmaxf(w, 0.f);
        u16 bb = f2bf(w);
        if (e < 4) ((u16*)&o0)[e] = bb; else ((u16*)&o1)[e - 4] = bb;
    }
    *(ushort4*)hp = o0;
    *(ushort4*)(hp + 4) = o1;
}

// ---------------------------------------------------------------------------
// Fused codebook pass: exact fp32 norms + bf16(-2E) copy + keys/accs init.
// grid = HQ*VOCAB/4 = 8192 blocks; blocks 0..63 also init keys[16384].
// ---------------------------------------------------------------------------
__global__ __launch_bounds__(256) void enorm_k(
    const float* __restrict__ cb, float* __restrict__ enorm,
    u16* __restrict__ cbb, u64* __restrict__ keys, double* __restrict__ accs)
{
    if (blockIdx.x < 64) keys[blockIdx.x * 256 + threadIdx.x] = ~0ull;
    if (blockIdx.x == 64 && threadIdx.x < 2) accs[threadIdx.x] = 0.0;
    const int row  = blockIdx.x * 4 + (threadIdx.x >> 6);
    const int lane = threadIdx.x & 63;
    const size_t off = (size_t)row * LAT + lane * 4;
    float4 v = *(const float4*)(cb + off);
    ushort4 o;
    o.x = f2bf(-2.f * v.x); o.y = f2bf(-2.f * v.y);
    o.z = f2bf(-2.f * v.z); o.w = f2bf(-2.f * v.w);
    *(ushort4*)(cbb + off) = o;
    float s = v.x * v.x + v.y * v.y + v.z * v.z + v.w * v.w;
#pragma unroll
    for (int off2 = 32; off2 >= 1; off2 >>= 1) s += __shfl_xor(s, off2);
    if (lane == 0) enorm[row] = s;
}

// fp32 -> bf16 bulk convert (4 elems/thread)
__global__ __launch_bounds__(256) void f2bf_k(
    const float* __restrict__ in, u16* __restrict__ out)
{
    size_t i = ((size_t)blockIdx.x * 256 + threadIdx.x) * 4;
    float4 v = *(const float4*)(in + i);
    ushort4 o;
    o.x = f2bf(v.x); o.y = f2bf(v.y); o.z = f2bf(v.z); o.w = f2bf(v.w);
    *(ushort4*)(out + i) = o;
}

// ---------------------------------------------------------------------------
// Distance + argmin via bf16 MFMA — round-7 restructure:
//  * A fragments (full K=256 for this wave's 32 rows) preloaded to registers:
//    no A staging, no A LDS reads; per-k0 staging halves (B only).
//  * B double-buffered: next chunk's global_load_lds issues AFTER the barrier
//    and drains at the NEXT barrier -> staging overlaps the compute phase
//    (one barrier per k0 instead of stage->immediate-drain).
//  * Wave = 32 m x 128 v (8 n-tiles); epilogue folds 8 candidates (ascending
//    v, strict < => first-min), one pack + 4-lane butterfly + direct
//    atomicMin (32/block, no shk, no extra barrier).
// launch_bounds(256,3): ~165 VGPR budget (acc 64 + A-frags 64 + rest).
// ---------------------------------------------------------------------------
__global__ __launch_bounds__(256, 3) void dist_mfma_k(
    const u16* __restrict__ Abf, const u16* __restrict__ Bneg2,
    const float* __restrict__ enorm, u64* __restrict__ keys)
{
    __shared__ u16 Bs[2][128 * 64];

    const int tid = threadIdx.x;
    const int wv  = tid >> 6, lane = tid & 63;
    const int m_  = lane & 15, g   = lane >> 4;
    const int m0  = blockIdx.x * 128;
    const int n0  = blockIdx.y * 128;

    // preload this wave's entire A (rows wv*32..+32, K=256) into registers
    bf16x8 af[2][8];
    const u16* Arow = Abf + (size_t)(m0 + wv * 32 + m_) * LAT + g * 8;
#pragma unroll
    for (int mi = 0; mi < 2; ++mi)
#pragma unroll
        for (int kb = 0; kb < 8; ++kb)
            af[mi][kb] = *(const bf16x8*)(Arow + mi * 16 * LAT + kb * 32);

    // acc starts at ||E_v||^2; MFMA adds (-2E)·r => acc = score
    f32x4 acc[2][8];
#pragma unroll
    for (int ni = 0; ni < 8; ++ni) {
        const float en = enorm[n0 + ni * 16 + m_];
        acc[0][ni] = f32x4{en, en, en, en};
        acc[1][ni] = f32x4{en, en, en, en};
    }

    const u16* Bblk = Bneg2 + (size_t)n0 * LAT;
    // stage first B chunk into buffer 0
#pragma unroll
    for (int c = 0; c < 4; ++c) {
        const int ci = (wv * 4 + c) * 64 + lane;
        const int r  = ci >> 3;
        const int cc = ci & 7;
        const int kc = (cc ^ (r & 7)) << 3;
        GL2LDS(Bblk + (size_t)r * LAT + kc, &Bs[0][(wv * 4 + c) * 512]);
    }

#pragma unroll
    for (int k0i = 0; k0i < 4; ++k0i) {
        __syncthreads();                       // buffer k0i&1 ready
        if (k0i < 3) {                         // prefetch next buffer
            const int k0n = (k0i + 1) * 64;
#pragma unroll
            for (int c = 0; c < 4; ++c) {
                const int ci = (wv * 4 + c) * 64 + lane;
                const int r  = ci >> 3;
                const int cc = ci & 7;
                const int kc = (cc ^ (r & 7)) << 3;
                GL2LDS(Bblk + (size_t)r * LAT + k0n + kc,
                       &Bs[(k0i + 1) & 1][(wv * 4 + c) * 512]);
            }
        }
        const u16* bsc = Bs[k0i & 1];
#pragma unroll
        for (int ks = 0; ks < 2; ++ks) {
            const int kb  = k0i * 2 + ks;
            const int ccw = ks * 4 + g;
            const int sw  = (ccw ^ (m_ & 7)) << 3;
#pragma unroll
            for (int nn = 0; nn < 2; ++nn) {
                bf16x8 bfr[4];
#pragma unroll
                for (int q = 0; q < 4; ++q) {
                    const int row = (nn * 4 + q) * 16 + m_;
                    bfr[q] = *(const bf16x8*)&bsc[row * 64 + sw];
                }
#pragma unroll
                for (int mi = 0; mi < 2; ++mi)
#pragma unroll
                    for (int q = 0; q < 4; ++q)
                        acc[mi][nn * 4 + q] =
                            __builtin_amdgcn_mfma_f32_16x16x32_bf16(
                                af[mi][kb], bfr[q], acc[mi][nn * 4 + q], 0, 0, 0);
            }
        }
    }

#pragma unroll
    for (int mi = 0; mi < 2; ++mi)
#pragma unroll
        for (int j = 0; j < 4; ++j) {
            float bs_ = acc[mi][0][j];
            int   bi_ = n0 + m_;
#pragma unroll
            for (int ni = 1; ni < 8; ++ni) {
                const float s = acc[mi][ni][j];
                const int   v = n0 + ni * 16 + m_;
                if (s < bs_) { bs_ = s; bi_ = v; }
            }
            u64 best = ((u64)float_to_ordered(bs_) << 32) | (unsigned)bi_;
#pragma unroll
            for (int mask = 1; mask <= 8; mask <<= 1) {
                u64 o = __shfl_xor(best, mask);
                best = o < best ? o : best;
            }
            if (m_ == 0)
                atomicMin(&keys[m0 + wv * 32 + mi * 16 + g * 4 + j], best);
        }
}

// ---------------------------------------------------------------------------
// Gather chosen code (fp32 exact), update residual, accumulate
// sum(resid_new^2), reset keys for the next level.
// LAST: skip resid/rbf stores, write qbf = f2bf(latent - resid_new) instead.
// ---------------------------------------------------------------------------
template<bool LAST>
__global__ __launch_bounds__(256) void vq_update_k(
    float* __restrict__ resid, u16* __restrict__ aux,   // aux = rbf or qbf
    const float* __restrict__ latent,
    const float* __restrict__ E,
    u64* __restrict__ keys, double* __restrict__ acc)
{
    __shared__ float red[4];
    const int tid = threadIdx.x;
    const int base = blockIdx.x * 16;
    float lsum = 0.f;
    for (int r = 0; r < 16; ++r) {
        const int row = base + r;
        const int idx = (int)(keys[row] & 0xFFFFFFFFull);
        const float q = E[(size_t)idx * LAT + tid];
        float v = resid[(size_t)row * LAT + tid] - q;
        if constexpr (LAST) {
            aux[(size_t)row * LAT + tid] =
                f2bf(latent[(size_t)row * LAT + tid] - v);
        } else {
            resid[(size_t)row * LAT + tid] = v;
            aux[(size_t)row * LAT + tid] = f2bf(v);
        }
        lsum = fmaf(v, v, lsum);
    }
    if (!LAST && tid < 16) keys[base + tid] = ~0ull;
#pragma unroll
    for (int off = 32; off >= 1; off >>= 1) lsum += __shfl_xor(lsum, off);
    if ((tid & 63) == 0) red[tid >> 6] = lsum;
    __syncthreads();
    if (tid == 0) atomicAdd(acc, (double)(red[0] + red[1] + red[2] + red[3]));
}

__global__ void finalize_k(const double* __restrict__ acc, float* __restrict__ out) {
    double total = 1.5 * acc[0] / (double)((size_t)N_ROWS * LAT)
                 + 0.5 * acc[1] / (double)((size_t)N_ROWS * OBS);
    out[0] = (float)total;
}

// ---------------------------------------------------------------------------
extern "C" void kernel_launch(void* const* d_in, const int* in_sizes, int n_in,
                              void* d_out, int out_size, void* d_ws, size_t ws_size,
                              hipStream_t stream)
{
    const float* x      = (const float*)d_in[0];
    const float* cb     = (const float*)d_in[1];
    const float* enc_w1 = (const float*)d_in[2];
    const float* enc_b1 = (const float*)d_in[3];
    const float* ln_g   = (const float*)d_in[4];
    const float* ln_b   = (const float*)d_in[5];
    const float* enc_w2 = (const float*)d_in[6];
    const float* enc_b2 = (const float*)d_in[7];
    const float* dec_w1 = (const float*)d_in[8];
    const float* dec_b1 = (const float*)d_in[9];
    const float* dec_w2 = (const float*)d_in[10];
    const float* dec_b2 = (const float*)d_in[11];

    char* ws = (char*)d_ws;
    const size_t MB = 1ull << 20;
    // 0-64:   hbuf (h_bf for GEMM1->GEMM2, then dh_bf for GEMM3->GEMM4)
    // 64-80:  cbb (-2E bf16, written by enorm_k at start, live all launch)
    // 80-88:  rbf   88-96: qbf
    // 96-112: latent (xbf overlaps here pre-GEMM2; xbf dead before GEMM2 writes)
    // 112-128: resid   128-138: weights   138+: enorm/keys/accs
    u16* hbuf = (u16*)ws;
    u16* cbb  = (u16*)(ws + 64 * MB);
    u16* rbf  = (u16*)(ws + 80 * MB);
    u16* qbf  = (u16*)(ws + 88 * MB);
    u16* xbf  = (u16*)(ws + 96 * MB);              // overlaps latent (dead by GEMM2)
    float* latent = (float*)(ws + 96 * MB);
    float* resid  = (float*)(ws + 112 * MB);
    u16* w1T  = (u16*)(ws + 128 * MB);   // [2048,1024]
    u16* w2T  = (u16*)(ws + 132 * MB);   // [256,2048]
    u16* wd1T = (u16*)(ws + 133 * MB);   // [2048,256]
    u16* wd2T = (u16*)(ws + 134 * MB);   // [1024,2048]
    float* enorm = (float*)(ws + 138 * MB);
    u64*   keys  = (u64*)(ws + 138 * MB + 131072);
    double* accs = (double*)(ws + 138 * MB + 262144);

    // fused: enorm + (-2E bf16) + keys/accs init
    enorm_k<<<HQ * VOCAB / 4, 256, 0, stream>>>(cb, enorm, cbb, keys, accs);

    // weight transposes + x conversion
    tpose_bf_k<<<dim3(HID / 32, OBS / 32), 256, 0, stream>>>(enc_w1, w1T, OBS, HID);
    tpose_bf_k<<<dim3(LAT / 32, HID / 32), 256, 0, stream>>>(enc_w2, w2T, HID, LAT);
    tpose_bf_k<<<dim3(HID / 32, LAT / 32), 256, 0, stream>>>(dec_w1, wd1T, LAT, HID);
    tpose_bf_k<<<dim3(OBS / 32, HID / 32), 256, 0, stream>>>(dec_w2, wd2T, HID, OBS);
    f2bf_k<<<(int)((size_t)N_ROWS * OBS / 1024), 256, 0, stream>>>(x, xbf);

    // encoder: GEMM1 -> LN+ReLU -> GEMM2 (64-tile)
    mfma_gemm_k<0><<<dim3(N_ROWS / 128, HID / 128), 256, 0, stream>>>(
        xbf, w1T, enc_b1, hbuf, nullptr, nullptr, OBS, HID);
    ln_relu_bf_k<<<N_ROWS, 256, 0, stream>>>(hbuf, ln_g, ln_b);
    gemm2_k<<<dim3(N_ROWS / 64, LAT / 64), 256, 0, stream>>>(
        hbuf, w2T, enc_b2, latent, resid, rbf);

    for (int l = 0; l < HQ; ++l) {
        dist_mfma_k<<<dim3(N_ROWS / 128, VOCAB / 128), 256, 0, stream>>>(
            rbf, cbb + (size_t)l * VOCAB * LAT, enorm + (size_t)l * VOCAB, keys);
        if (l < HQ - 1)
            vq_update_k<false><<<N_ROWS / 16, 256, 0, stream>>>(
                resid, rbf, nullptr, cb + (size_t)l * VOCAB * LAT, keys, accs);
        else
            vq_update_k<true><<<N_ROWS / 16, 256, 0, stream>>>(
                resid, qbf, latent, cb + (size_t)l * VOCAB * LAT, keys, accs);
    }

    // decoder GEMM3 -> GEMM4(+loss)
    mfma_gemm_k<1><<<dim3(N_ROWS / 128, HID / 128), 256, 0, stream>>>(
        qbf, wd1T, dec_b1, hbuf, nullptr, nullptr, LAT, HID);
    mfma_gemm_k<3><<<dim3(N_ROWS / 128, OBS / 128), 256, 0, stream>>>(
        hbuf, wd2T, dec_b2, nullptr, x, accs + 1, HID, OBS);

    finalize_k<<<1, 1, 0, stream>>>(accs, (float*)d_out);
}

// Round 8
// 891.085 us; speedup vs baseline: 1.0360x; 1.0360x over previous
//
#include <hip/hip_runtime.h>

#define N_ROWS 16384
#define OBS    1024
#define HID    2048
#define LAT    256
#define VOCAB  8192
#define HQ     4
#define LN_EPS 1e-5f

typedef unsigned short u16;
typedef unsigned long long u64;
typedef __bf16 bf16x8 __attribute__((ext_vector_type(8)));
typedef float  f32x4  __attribute__((ext_vector_type(4)));

static __device__ __forceinline__ unsigned int float_to_ordered(float f) {
    unsigned int u = __float_as_uint(f);
    return (u & 0x80000000u) ? ~u : (u | 0x80000000u);
}
// fp32 -> bf16 round-to-nearest-even
static __device__ __forceinline__ u16 f2bf(float f) {
    unsigned int u = __float_as_uint(f);
    unsigned int r = u + 0x7FFFu + ((u >> 16) & 1u);
    return (u16)(r >> 16);
}
static __device__ __forceinline__ float bf2f(u16 u) {
    return __uint_as_float((unsigned int)u << 16);
}

#define GL2LDS(gp, lp) __builtin_amdgcn_global_load_lds( \
    (const __attribute__((address_space(1))) void*)(gp), \
    (__attribute__((address_space(3))) void*)(lp), 16, 0, 0)

// ---------------------------------------------------------------------------
// bf16 MFMA GEMM, 128x128 tile, C = A @ B^T + bias. (verified rounds 3-6)
// EPI 0: store bf16 C.  1: relu + store bf16 C.  3: fused loss, no store.
// ---------------------------------------------------------------------------
template<int EPI>
__global__ __launch_bounds__(256, 4) void mfma_gemm_k(
    const u16* __restrict__ Abf, const u16* __restrict__ Bbf,
    const float* __restrict__ bias,
    u16* __restrict__ Cbf,
    const float* __restrict__ X, double* __restrict__ lacc,
    int K, int Nd)
{
    __shared__ u16 As[128 * 64];
    __shared__ u16 Bs[128 * 64];

    const int tid  = threadIdx.x;
    const int wv   = tid >> 6, lane = tid & 63;
    const int wm   = wv & 1,   wn   = wv >> 1;
    const int m_   = lane & 15, g   = lane >> 4;
    const int m0   = blockIdx.x * 128;
    const int n0   = blockIdx.y * 128;

    f32x4 acc[4][4];
#pragma unroll
    for (int i = 0; i < 4; ++i)
#pragma unroll
        for (int j = 0; j < 4; ++j)
            acc[i][j] = f32x4{0.f, 0.f, 0.f, 0.f};

    const u16* Ablk = Abf + (size_t)m0 * K;
    const u16* Bblk = Bbf + (size_t)n0 * K;

    for (int k0 = 0; k0 < K; k0 += 64) {
#pragma unroll
        for (int c = 0; c < 4; ++c) {
            const int ci = (wv * 4 + c) * 64 + lane;
            const int r  = ci >> 3;
            const int cc = ci & 7;
            const int kc = (cc ^ (r & 7)) << 3;
            GL2LDS(Ablk + (size_t)r * K + k0 + kc, As + (wv * 4 + c) * 512);
            GL2LDS(Bblk + (size_t)r * K + k0 + kc, Bs + (wv * 4 + c) * 512);
        }
        __syncthreads();
#pragma unroll
        for (int ks = 0; ks < 2; ++ks) {
            const int ccw = ks * 4 + g;
            const int sw  = (ccw ^ (m_ & 7)) << 3;
            bf16x8 af[4], bfr[4];
#pragma unroll
            for (int t = 0; t < 4; ++t) {
                af[t]  = *(const bf16x8*)&As[(wm * 64 + t * 16 + m_) * 64 + sw];
                bfr[t] = *(const bf16x8*)&Bs[(wn * 64 + t * 16 + m_) * 64 + sw];
            }
#pragma unroll
            for (int mi = 0; mi < 4; ++mi)
#pragma unroll
                for (int ni = 0; ni < 4; ++ni)
                    acc[mi][ni] = __builtin_amdgcn_mfma_f32_16x16x32_bf16(
                        af[mi], bfr[ni], acc[mi][ni], 0, 0, 0);
        }
        __syncthreads();
    }

    float bs[4];
#pragma unroll
    for (int ni = 0; ni < 4; ++ni) bs[ni] = bias[n0 + wn * 64 + ni * 16 + m_];

    if constexpr (EPI == 3) {
        float lsum = 0.f;
#pragma unroll
        for (int mi = 0; mi < 4; ++mi)
#pragma unroll
            for (int j = 0; j < 4; ++j) {
                const int row = m0 + wm * 64 + mi * 16 + g * 4 + j;
#pragma unroll
                for (int ni = 0; ni < 4; ++ni) {
                    const int col = n0 + wn * 64 + ni * 16 + m_;
                    float r = acc[mi][ni][j] + bs[ni] - X[(size_t)row * Nd + col];
                    lsum = fmaf(r, r, lsum);
                }
            }
#pragma unroll
        for (int off = 32; off >= 1; off >>= 1) lsum += __shfl_xor(lsum, off);
        __shared__ float red[4];
        if (lane == 0) red[wv] = lsum;
        __syncthreads();
        if (tid == 0)
            atomicAdd(lacc, (double)(red[0] + red[1] + red[2] + red[3]));
    } else {
#pragma unroll
        for (int mi = 0; mi < 4; ++mi)
#pragma unroll
            for (int j = 0; j < 4; ++j) {
                const int row = m0 + wm * 64 + mi * 16 + g * 4 + j;
#pragma unroll
                for (int ni = 0; ni < 4; ++ni) {
                    const int col = n0 + wn * 64 + ni * 16 + m_;
                    float v = acc[mi][ni][j] + bs[ni];
                    if constexpr (EPI == 1) v = fmaxf(v, 0.f);
                    Cbf[(size_t)row * Nd + col] = f2bf(v);
                }
            }
    }
}

// ---------------------------------------------------------------------------
// GEMM2 dedicated kernel: 64x64 tile (1024 blocks = 4/CU vs 256 at 128-tile).
// latent = h @ w2T^T + b2; writes fp32 latent + fp32 resid + bf16 rbf.
// ---------------------------------------------------------------------------
__global__ __launch_bounds__(256, 4) void gemm2_k(
    const u16* __restrict__ Abf, const u16* __restrict__ Bbf,
    const float* __restrict__ bias,
    float* __restrict__ lat, float* __restrict__ resid, u16* __restrict__ rbf)
{
    __shared__ u16 As[64 * 64];
    __shared__ u16 Bs[64 * 64];

    const int tid = threadIdx.x;
    const int wv  = tid >> 6, lane = tid & 63;
    const int wm  = wv & 1,   wn   = wv >> 1;
    const int m_  = lane & 15, g   = lane >> 4;
    const int m0  = blockIdx.x * 64;
    const int n0  = blockIdx.y * 64;

    f32x4 acc[2][2];
#pragma unroll
    for (int i = 0; i < 2; ++i)
#pragma unroll
        for (int j = 0; j < 2; ++j)
            acc[i][j] = f32x4{0.f, 0.f, 0.f, 0.f};

    const u16* Ablk = Abf + (size_t)m0 * HID;
    const u16* Bblk = Bbf + (size_t)n0 * HID;

    for (int k0 = 0; k0 < HID; k0 += 64) {
#pragma unroll
        for (int c = 0; c < 2; ++c) {
            const int ci = (wv * 2 + c) * 64 + lane;
            const int r  = ci >> 3;
            const int cc = ci & 7;
            const int kc = (cc ^ (r & 7)) << 3;
            GL2LDS(Ablk + (size_t)r * HID + k0 + kc, As + (wv * 2 + c) * 512);
            GL2LDS(Bblk + (size_t)r * HID + k0 + kc, Bs + (wv * 2 + c) * 512);
        }
        __syncthreads();
#pragma unroll
        for (int ks = 0; ks < 2; ++ks) {
            const int ccw = ks * 4 + g;
            const int sw  = (ccw ^ (m_ & 7)) << 3;
            bf16x8 af[2], bfr[2];
#pragma unroll
            for (int t = 0; t < 2; ++t) {
                af[t]  = *(const bf16x8*)&As[(wm * 32 + t * 16 + m_) * 64 + sw];
                bfr[t] = *(const bf16x8*)&Bs[(wn * 32 + t * 16 + m_) * 64 + sw];
            }
#pragma unroll
            for (int mi = 0; mi < 2; ++mi)
#pragma unroll
                for (int ni = 0; ni < 2; ++ni)
                    acc[mi][ni] = __builtin_amdgcn_mfma_f32_16x16x32_bf16(
                        af[mi], bfr[ni], acc[mi][ni], 0, 0, 0);
        }
        __syncthreads();
    }

#pragma unroll
    for (int mi = 0; mi < 2; ++mi)
#pragma unroll
        for (int j = 0; j < 4; ++j) {
            const int row = m0 + wm * 32 + mi * 16 + g * 4 + j;
#pragma unroll
            for (int ni = 0; ni < 2; ++ni) {
                const int col = n0 + wn * 32 + ni * 16 + m_;
                float v = acc[mi][ni][j] + bias[col];
                lat  [(size_t)row * LAT + col] = v;
                resid[(size_t)row * LAT + col] = v;
                rbf  [(size_t)row * LAT + col] = f2bf(v);
            }
        }
}

// ---------------------------------------------------------------------------
// All 4 weight transposes in ONE launch: W fp32 [K,N] -> Wt bf16 [N,K].
// Flat 5120-block grid, range-select per weight.
// ---------------------------------------------------------------------------
__global__ __launch_bounds__(256) void tpose4_k(
    const float* __restrict__ W0, u16* __restrict__ T0,   // enc_w1 1024x2048
    const float* __restrict__ W1, u16* __restrict__ T1,   // enc_w2 2048x256
    const float* __restrict__ W2, u16* __restrict__ T2,   // dec_w1 256x2048
    const float* __restrict__ W3, u16* __restrict__ T3)   // dec_w2 2048x1024
{
    __shared__ u16 t[32][33];
    const int bid = blockIdx.x;
    const float* W; u16* T; int K, N, r;
    if (bid < 2048)      { W = W0; T = T0; K = OBS; N = HID; r = bid; }
    else if (bid < 2560) { W = W1; T = T1; K = HID; N = LAT; r = bid - 2048; }
    else if (bid < 3072) { W = W2; T = T2; K = LAT; N = HID; r = bid - 2560; }
    else                 { W = W3; T = T3; K = HID; N = OBS; r = bid - 3072; }
    const int nb = N >> 5;
    const int n0 = (r % nb) * 32, k0 = (r / nb) * 32;
    const int lx = threadIdx.x & 31, ly = threadIdx.x >> 5;
#pragma unroll
    for (int i = 0; i < 4; ++i)
        t[ly + 8 * i][lx] = f2bf(W[(size_t)(k0 + ly + 8 * i) * N + n0 + lx]);
    __syncthreads();
#pragma unroll
    for (int i = 0; i < 4; ++i)
        T[(size_t)(n0 + ly + 8 * i) * K + k0 + lx] = t[lx][ly + 8 * i];
}

// ---------------------------------------------------------------------------
// LayerNorm + ReLU in place on bf16 h (fp32 math), one block per row of 2048.
// ---------------------------------------------------------------------------
__device__ __forceinline__ float block_reduce_bcast(float v, float* scratch) {
#pragma unroll
    for (int off = 32; off >= 1; off >>= 1) v += __shfl_xor(v, off);
    const int tid = threadIdx.x;
    __syncthreads();
    if ((tid & 63) == 0) scratch[tid >> 6] = v;
    __syncthreads();
    return scratch[0] + scratch[1] + scratch[2] + scratch[3];
}

__global__ __launch_bounds__(256) void ln_relu_bf_k(
    u16* __restrict__ h, const float* __restrict__ g, const float* __restrict__ b)
{
    __shared__ float scratch[4];
    const int tid = threadIdx.x;
    u16* hp = h + (size_t)blockIdx.x * HID + tid * 8;

    ushort4 r0 = *(const ushort4*)hp;
    ushort4 r1 = *(const ushort4*)(hp + 4);
    float v[8] = {bf2f(r0.x), bf2f(r0.y), bf2f(r0.z), bf2f(r0.w),
                  bf2f(r1.x), bf2f(r1.y), bf2f(r1.z), bf2f(r1.w)};

    float s = 0.f;
#pragma unroll
    for (int e = 0; e < 8; ++e) s += v[e];
    const float mu = block_reduce_bcast(s, scratch) * (1.f / HID);

    float vs = 0.f;
#pragma unroll
    for (int e = 0; e < 8; ++e) { float d = v[e] - mu; vs = fmaf(d, d, vs); }
    const float var = block_reduce_bcast(vs, scratch) * (1.f / HID);
    const float rs = rsqrtf(var + LN_EPS);

    ushort4 o0, o1;
#pragma unroll
    for (int e = 0; e < 8; ++e) {
        const int col = tid * 8 + e;
        float w = (v[e] - mu) * rs * g[col] + b[col];
        w = fmaxf(w, 0.f);
        u16 bb = f2bf(w);
        if (e < 4) ((u16*)&o0)[e] = bb; else ((u16*)&o1)[e - 4] = bb;
    }
    *(ushort4*)hp = o0;
    *(ushort4*)(hp + 4) = o1;
}

// ---------------------------------------------------------------------------
// Fused codebook pass: exact fp32 norms + bf16(-2E) copy + keys/accs init.
// grid = HQ*VOCAB/4 = 8192 blocks; blocks 0..63 also init keys[16384].
// ---------------------------------------------------------------------------
__global__ __launch_bounds__(256) void enorm_k(
    const float* __restrict__ cb, float* __restrict__ enorm,
    u16* __restrict__ cbb, u64* __restrict__ keys, double* __restrict__ accs)
{
    if (blockIdx.x < 64) keys[blockIdx.x * 256 + threadIdx.x] = ~0ull;
    if (blockIdx.x == 64 && threadIdx.x < 2) accs[threadIdx.x] = 0.0;
    const int row  = blockIdx.x * 4 + (threadIdx.x >> 6);
    const int lane = threadIdx.x & 63;
    const size_t off = (size_t)row * LAT + lane * 4;
    float4 v = *(const float4*)(cb + off);
    ushort4 o;
    o.x = f2bf(-2.f * v.x); o.y = f2bf(-2.f * v.y);
    o.z = f2bf(-2.f * v.z); o.w = f2bf(-2.f * v.w);
    *(ushort4*)(cbb + off) = o;
    float s = v.x * v.x + v.y * v.y + v.z * v.z + v.w * v.w;
#pragma unroll
    for (int off2 = 32; off2 >= 1; off2 >>= 1) s += __shfl_xor(s, off2);
    if (lane == 0) enorm[row] = s;
}

// fp32 -> bf16 bulk convert (4 elems/thread)
__global__ __launch_bounds__(256) void f2bf_k(
    const float* __restrict__ in, u16* __restrict__ out)
{
    size_t i = ((size_t)blockIdx.x * 256 + threadIdx.x) * 4;
    float4 v = *(const float4*)(in + i);
    ushort4 o;
    o.x = f2bf(v.x); o.y = f2bf(v.y); o.z = f2bf(v.z); o.w = f2bf(v.w);
    *(ushort4*)(out + i) = o;
}

// ---------------------------------------------------------------------------
// Distance + argmin via bf16 MFMA — round-6 version (proven 113 us):
// 128M x 128V per block, 8192 blocks, launch_bounds(256,4), ||E||^2 folded
// into accumulator init (codebook pre-scaled by -2 => acc = score).
// ---------------------------------------------------------------------------
__global__ __launch_bounds__(256, 4) void dist_mfma_k(
    const u16* __restrict__ Abf, const u16* __restrict__ Bneg2,
    const float* __restrict__ enorm, u64* __restrict__ keys)
{
    __shared__ u16 As[128 * 64];
    __shared__ u16 Bs[128 * 64];
    __shared__ u64 shk[128][2];

    const int tid  = threadIdx.x;
    const int wv   = tid >> 6, lane = tid & 63;
    const int wm   = wv & 1,   wn   = wv >> 1;
    const int m_   = lane & 15, g   = lane >> 4;
    const int m0   = blockIdx.x * 128;
    const int n0   = blockIdx.y * 128;

    f32x4 acc[4][4];
#pragma unroll
    for (int ni = 0; ni < 4; ++ni) {
        const float en = enorm[n0 + wn * 64 + ni * 16 + m_];
#pragma unroll
        for (int mi = 0; mi < 4; ++mi)
            acc[mi][ni] = f32x4{en, en, en, en};
    }

    const u16* Ablk = Abf   + (size_t)m0 * LAT;
    const u16* Bblk = Bneg2 + (size_t)n0 * LAT;

    for (int k0 = 0; k0 < LAT; k0 += 64) {
#pragma unroll
        for (int c = 0; c < 4; ++c) {
            const int ci = (wv * 4 + c) * 64 + lane;
            const int r  = ci >> 3;
            const int cc = ci & 7;
            const int kc = (cc ^ (r & 7)) << 3;
            GL2LDS(Ablk + (size_t)r * LAT + k0 + kc, As + (wv * 4 + c) * 512);
            GL2LDS(Bblk + (size_t)r * LAT + k0 + kc, Bs + (wv * 4 + c) * 512);
        }
        __syncthreads();
#pragma unroll
        for (int ks = 0; ks < 2; ++ks) {
            const int ccw = ks * 4 + g;
            const int sw  = (ccw ^ (m_ & 7)) << 3;
            bf16x8 af[4], bfr[4];
#pragma unroll
            for (int t = 0; t < 4; ++t) {
                af[t]  = *(const bf16x8*)&As[(wm * 64 + t * 16 + m_) * 64 + sw];
                bfr[t] = *(const bf16x8*)&Bs[(wn * 64 + t * 16 + m_) * 64 + sw];
            }
#pragma unroll
            for (int mi = 0; mi < 4; ++mi)
#pragma unroll
                for (int ni = 0; ni < 4; ++ni)
                    acc[mi][ni] = __builtin_amdgcn_mfma_f32_16x16x32_bf16(
                        af[mi], bfr[ni], acc[mi][ni], 0, 0, 0);
        }
        __syncthreads();
    }

#pragma unroll
    for (int mi = 0; mi < 4; ++mi)
#pragma unroll
        for (int j = 0; j < 4; ++j) {
            float bs_ = acc[mi][0][j];
            int   bi_ = n0 + wn * 64 + m_;
#pragma unroll
            for (int ni = 1; ni < 4; ++ni) {
                const float s = acc[mi][ni][j];
                const int   v = n0 + wn * 64 + ni * 16 + m_;
                if (s < bs_) { bs_ = s; bi_ = v; }
            }
            u64 best = ((u64)float_to_ordered(bs_) << 32) | (unsigned)bi_;
#pragma unroll
            for (int mask = 1; mask <= 8; mask <<= 1) {
                u64 o = __shfl_xor(best, mask);
                best = o < best ? o : best;
            }
            if (m_ == 0) shk[wm * 64 + mi * 16 + g * 4 + j][wn] = best;
        }
    __syncthreads();
    if (tid < 128) {
        u64 a = shk[tid][0], b = shk[tid][1];
        atomicMin(&keys[m0 + tid], a < b ? a : b);
    }
}

// ---------------------------------------------------------------------------
// Gather chosen code (fp32 exact), update residual, accumulate
// sum(resid_new^2), reset keys for the next level.
// LAST: skip resid/rbf stores, write qbf = f2bf(latent - resid_new) instead.
// ---------------------------------------------------------------------------
template<bool LAST>
__global__ __launch_bounds__(256) void vq_update_k(
    float* __restrict__ resid, u16* __restrict__ aux,   // aux = rbf or qbf
    const float* __restrict__ latent,
    const float* __restrict__ E,
    u64* __restrict__ keys, double* __restrict__ acc)
{
    __shared__ float red[4];
    const int tid = threadIdx.x;
    const int base = blockIdx.x * 16;
    float lsum = 0.f;
    for (int r = 0; r < 16; ++r) {
        const int row = base + r;
        const int idx = (int)(keys[row] & 0xFFFFFFFFull);
        const float q = E[(size_t)idx * LAT + tid];
        float v = resid[(size_t)row * LAT + tid] - q;
        if constexpr (LAST) {
            aux[(size_t)row * LAT + tid] =
                f2bf(latent[(size_t)row * LAT + tid] - v);
        } else {
            resid[(size_t)row * LAT + tid] = v;
            aux[(size_t)row * LAT + tid] = f2bf(v);
        }
        lsum = fmaf(v, v, lsum);
    }
    if (!LAST && tid < 16) keys[base + tid] = ~0ull;
#pragma unroll
    for (int off = 32; off >= 1; off >>= 1) lsum += __shfl_xor(lsum, off);
    if ((tid & 63) == 0) red[tid >> 6] = lsum;
    __syncthreads();
    if (tid == 0) atomicAdd(acc, (double)(red[0] + red[1] + red[2] + red[3]));
}

__global__ void finalize_k(const double* __restrict__ acc, float* __restrict__ out) {
    double total = 1.5 * acc[0] / (double)((size_t)N_ROWS * LAT)
                 + 0.5 * acc[1] / (double)((size_t)N_ROWS * OBS);
    out[0] = (float)total;
}

// ---------------------------------------------------------------------------
extern "C" void kernel_launch(void* const* d_in, const int* in_sizes, int n_in,
                              void* d_out, int out_size, void* d_ws, size_t ws_size,
                              hipStream_t stream)
{
    const float* x      = (const float*)d_in[0];
    const float* cb     = (const float*)d_in[1];
    const float* enc_w1 = (const float*)d_in[2];
    const float* enc_b1 = (const float*)d_in[3];
    const float* ln_g   = (const float*)d_in[4];
    const float* ln_b   = (const float*)d_in[5];
    const float* enc_w2 = (const float*)d_in[6];
    const float* enc_b2 = (const float*)d_in[7];
    const float* dec_w1 = (const float*)d_in[8];
    const float* dec_b1 = (const float*)d_in[9];
    const float* dec_w2 = (const float*)d_in[10];
    const float* dec_b2 = (const float*)d_in[11];

    char* ws = (char*)d_ws;
    const size_t MB = 1ull << 20;
    u16* hbuf = (u16*)ws;                          // 0-64MB: h_bf then dh_bf
    u16* cbb  = (u16*)(ws + 64 * MB);              // -2E bf16, live all launch
    u16* rbf  = (u16*)(ws + 80 * MB);
    u16* qbf  = (u16*)(ws + 88 * MB);
    u16* xbf  = (u16*)(ws + 96 * MB);              // overlaps latent (dead by GEMM2)
    float* latent = (float*)(ws + 96 * MB);
    float* resid  = (float*)(ws + 112 * MB);
    u16* w1T  = (u16*)(ws + 128 * MB);   // [2048,1024]
    u16* w2T  = (u16*)(ws + 132 * MB);   // [256,2048]
    u16* wd1T = (u16*)(ws + 133 * MB);   // [2048,256]
    u16* wd2T = (u16*)(ws + 134 * MB);   // [1024,2048]
    float* enorm = (float*)(ws + 138 * MB);
    u64*   keys  = (u64*)(ws + 138 * MB + 131072);
    double* accs = (double*)(ws + 138 * MB + 262144);

    // fused: enorm + (-2E bf16) + keys/accs init
    enorm_k<<<HQ * VOCAB / 4, 256, 0, stream>>>(cb, enorm, cbb, keys, accs);

    // all weight transposes in one launch + x conversion
    tpose4_k<<<5120, 256, 0, stream>>>(enc_w1, w1T, enc_w2, w2T,
                                       dec_w1, wd1T, dec_w2, wd2T);
    f2bf_k<<<(int)((size_t)N_ROWS * OBS / 1024), 256, 0, stream>>>(x, xbf);

    // encoder: GEMM1 -> LN+ReLU -> GEMM2 (64-tile)
    mfma_gemm_k<0><<<dim3(N_ROWS / 128, HID / 128), 256, 0, stream>>>(
        xbf, w1T, enc_b1, hbuf, nullptr, nullptr, OBS, HID);
    ln_relu_bf_k<<<N_ROWS, 256, 0, stream>>>(hbuf, ln_g, ln_b);
    gemm2_k<<<dim3(N_ROWS / 64, LAT / 64), 256, 0, stream>>>(
        hbuf, w2T, enc_b2, latent, resid, rbf);

    for (int l = 0; l < HQ; ++l) {
        dist_mfma_k<<<dim3(N_ROWS / 128, VOCAB / 128), 256, 0, stream>>>(
            rbf, cbb + (size_t)l * VOCAB * LAT, enorm + (size_t)l * VOCAB, keys);
        if (l < HQ - 1)
            vq_update_k<false><<<N_ROWS / 16, 256, 0, stream>>>(
                resid, rbf, nullptr, cb + (size_t)l * VOCAB * LAT, keys, accs);
        else
            vq_update_k<true><<<N_ROWS / 16, 256, 0, stream>>>(
                resid, qbf, latent, cb + (size_t)l * VOCAB * LAT, keys, accs);
    }

    // decoder GEMM3 -> GEMM4(+loss)
    mfma_gemm_k<1><<<dim3(N_ROWS / 128, HID / 128), 256, 0, stream>>>(
        qbf, wd1T, dec_b1, hbuf, nullptr, nullptr, LAT, HID);
    mfma_gemm_k<3><<<dim3(N_ROWS / 128, OBS / 128), 256, 0, stream>>>(
        hbuf, wd2T, dec_b2, nullptr, x, accs + 1, HID, OBS);

    finalize_k<<<1, 1, 0, stream>>>(accs, (float*)d_out);
}